// Round 1
// baseline (880.439 us; speedup 1.0000x reference)
//
#include <hip/hip_runtime.h>
#include <hip/hip_bf16.h>
#include <math.h>

// QuantumNeuralLayer: y = cat_k(x@W16_k^T + b16_k); fused = y@Wf^T + bf; LN; exact GELU
// Collapsed: fused = x @ Weq^T + beq, Weq = Wf @ W16r  (275+69 GFLOP instead of 2.2 TFLOP)

typedef __bf16 bf16_t;
typedef __bf16 bf16x8 __attribute__((ext_vector_type(8)));
typedef __bf16 bf16x4 __attribute__((ext_vector_type(4)));
typedef float  f32x4  __attribute__((ext_vector_type(4)));

#define KC 32768   // concat dim = 16*2048
#define OD 2048    // output size
#define ID 2048    // input size
#define BSROWS 8192 // B*S

#define GLL16(g, l) __builtin_amdgcn_global_load_lds( \
    (const __attribute__((address_space(1))) void*)(g), \
    (__attribute__((address_space(3))) void*)(l), 16, 0, 0)

__device__ __forceinline__ float wave_sum(float v) {
#pragma unroll
  for (int o = 32; o > 0; o >>= 1) v += __shfl_down(v, o, 64);
  return v;
}

// ---------------- GEMM: C[m][n] (f32) = A[m][k] * B[n][k]^T, bf16 inputs -----------
// 128x128 tile, BK=32, 4 waves x (64x64 via 4x4 of 16x16x32 MFMA). m97 structure.
__global__ __launch_bounds__(256) void gemm_bt(
    const bf16_t* __restrict__ A, const bf16_t* __restrict__ B,
    float* __restrict__ C, int M, int N, int lda, int ldb, int Ks)
{
  __shared__ bf16_t As[128 * 32];
  __shared__ bf16_t Bs[128 * 32];
  const int tid  = threadIdx.x;
  const int lane = tid & 63;
  const int wave = tid >> 6;
  const int bm = blockIdx.y * 128;
  const int bn = blockIdx.x * 128;
  const int k0 = blockIdx.z * Ks;          // K-split offset
  float* Cz = C + (size_t)blockIdx.z * ((size_t)M * (size_t)N);

  f32x4 acc[4][4] = {};

  // staging: wave w fills rows [w*32, w*32+32) of each tile; lane covers
  // row (chunk*16 + lane>>2), k-offset (lane&3)*8, 16B each, LDS linear.
  const int srow  = wave * 32 + (lane >> 2);
  const int skoff = (lane & 3) * 8;
  const bf16_t* gA = A + (size_t)(bm + srow) * lda + k0 + skoff;
  const bf16_t* gB = B + (size_t)(bn + srow) * ldb + k0 + skoff;
  bf16_t* lA = &As[wave * 1024];
  bf16_t* lB = &Bs[wave * 1024];

  const int fr = lane & 15;          // fragment row/col
  const int fk = (lane >> 4) * 8;    // fragment k offset
  const int wr = (wave >> 1) * 64;   // wave output sub-tile
  const int wc = (wave & 1) * 64;

  for (int kk = 0; kk < Ks; kk += 32) {
    GLL16(gA,                     lA);
    GLL16(gA + (size_t)16 * lda,  lA + 512);
    GLL16(gB,                     lB);
    GLL16(gB + (size_t)16 * ldb,  lB + 512);
    gA += 32; gB += 32;
    __syncthreads();   // compiler drains vmcnt before barrier -> tiles ready

    bf16x8 af[4], bg[4];
#pragma unroll
    for (int m = 0; m < 4; ++m)
      af[m] = *reinterpret_cast<const bf16x8*>(&As[(wr + m * 16 + fr) * 32 + fk]);
#pragma unroll
    for (int n = 0; n < 4; ++n)
      bg[n] = *reinterpret_cast<const bf16x8*>(&Bs[(wc + n * 16 + fr) * 32 + fk]);
#pragma unroll
    for (int m = 0; m < 4; ++m)
#pragma unroll
      for (int n = 0; n < 4; ++n)
        acc[m][n] = __builtin_amdgcn_mfma_f32_16x16x32_bf16(af[m], bg[n], acc[m][n], 0, 0, 0);
    __syncthreads();   // protect LDS before next stage
  }

  // C/D layout (m89-verified): col = lane&15, row = (lane>>4)*4 + j
  const int cr = (lane >> 4) * 4;
  const int cc = lane & 15;
#pragma unroll
  for (int m = 0; m < 4; ++m)
#pragma unroll
    for (int n = 0; n < 4; ++n) {
      size_t base = (size_t)(bm + wr + m * 16 + cr) * N + (bn + wc + n * 16 + cc);
#pragma unroll
      for (int j = 0; j < 4; ++j)
        Cz[base + (size_t)j * N] = acc[m][n][j];
    }
}

// ---------------- Wf f32 -> bf16, and beq partial = sum_c b16[c]*Wf[o,c] ----------
__global__ void conv_wf_beq(const float* __restrict__ Wf, const float* __restrict__ b16,
                            bf16_t* __restrict__ Wf16, float* __restrict__ beq)
{
  const int o  = blockIdx.y;
  const int cb = blockIdx.x * 2048;
  const int t  = threadIdx.x;
  const size_t gbase = (size_t)o * KC + cb + t * 8;
  const float4 v0 = *(const float4*)(Wf + gbase);
  const float4 v1 = *(const float4*)(Wf + gbase + 4);
  const float4 b0 = *(const float4*)(b16 + cb + t * 8);
  const float4 b1 = *(const float4*)(b16 + cb + t * 8 + 4);
  bf16x8 r;
  r[0] = (bf16_t)v0.x; r[1] = (bf16_t)v0.y; r[2] = (bf16_t)v0.z; r[3] = (bf16_t)v0.w;
  r[4] = (bf16_t)v1.x; r[5] = (bf16_t)v1.y; r[6] = (bf16_t)v1.z; r[7] = (bf16_t)v1.w;
  *reinterpret_cast<bf16x8*>(Wf16 + gbase) = r;
  float s = v0.x * b0.x + v0.y * b0.y + v0.z * b0.z + v0.w * b0.w
          + v1.x * b1.x + v1.y * b1.y + v1.z * b1.z + v1.w * b1.w;
  s = wave_sum(s);
  __shared__ float red[4];
  if ((t & 63) == 0) red[t >> 6] = s;
  __syncthreads();
  if (t == 0) atomicAdd(beq + o, red[0] + red[1] + red[2] + red[3]);
}

// ---------------- W16 [c=k*O+o][i] f32 -> W16T [i][c] bf16 (tiled transpose) ------
__global__ void transpose_w16(const float* __restrict__ W, bf16_t* __restrict__ T)
{
  __shared__ bf16_t tile[64][65];
  const int cb = blockIdx.x * 64;
  const int ib = blockIdx.y * 64;
  const int tx = threadIdx.x & 63;
  const int ty = threadIdx.x >> 6;
#pragma unroll
  for (int r = ty; r < 64; r += 4)
    tile[r][tx] = (bf16_t)W[(size_t)(cb + r) * ID + ib + tx];
  __syncthreads();
#pragma unroll
  for (int r = ty; r < 64; r += 4)
    T[(size_t)(ib + r) * KC + cb + tx] = tile[tx][r];
}

// ---------------- x f32 -> bf16 ---------------------------------------------------
__global__ void conv_x(const float* __restrict__ X, bf16_t* __restrict__ X16)
{
  const size_t i = ((size_t)blockIdx.x * 256 + threadIdx.x) * 8;
  const float4 v0 = *(const float4*)(X + i);
  const float4 v1 = *(const float4*)(X + i + 4);
  bf16x8 r;
  r[0] = (bf16_t)v0.x; r[1] = (bf16_t)v0.y; r[2] = (bf16_t)v0.z; r[3] = (bf16_t)v0.w;
  r[4] = (bf16_t)v1.x; r[5] = (bf16_t)v1.y; r[6] = (bf16_t)v1.z; r[7] = (bf16_t)v1.w;
  *reinterpret_cast<bf16x8*>(X16 + i) = r;
}

// ---------------- reduce 4 K-split slabs -> Weq bf16 ------------------------------
__global__ void reduce_weq(const float* __restrict__ slabs, bf16_t* __restrict__ Weq)
{
  const size_t MN = (size_t)OD * ID;
  const size_t i = ((size_t)blockIdx.x * 256 + threadIdx.x) * 4;
  float4 a = *(const float4*)(slabs + i);
  float4 b = *(const float4*)(slabs + MN + i);
  float4 c = *(const float4*)(slabs + 2 * MN + i);
  float4 d = *(const float4*)(slabs + 3 * MN + i);
  bf16x4 r;
  r[0] = (bf16_t)(a.x + b.x + c.x + d.x);
  r[1] = (bf16_t)(a.y + b.y + c.y + d.y);
  r[2] = (bf16_t)(a.z + b.z + c.z + d.z);
  r[3] = (bf16_t)(a.w + b.w + c.w + d.w);
  *reinterpret_cast<bf16x4*>(Weq + i) = r;
}

// ---------------- bias + LayerNorm + exact GELU, one block per row ----------------
__global__ __launch_bounds__(256) void ln_gelu(
    const float* __restrict__ fused, const float* __restrict__ beq,
    const float* __restrict__ bfv, const float* __restrict__ gamma,
    const float* __restrict__ beta, float* __restrict__ out)
{
  const int row = blockIdx.x;
  const int t = threadIdx.x;
  const float* fr = fused + (size_t)row * OD;
  const int c0 = t * 8;
  float v[8];
  float s = 0.f, ss = 0.f;
#pragma unroll
  for (int j = 0; j < 2; ++j) {
    float4 x  = *(const float4*)(fr  + c0 + j * 4);
    float4 bq = *(const float4*)(beq + c0 + j * 4);
    float4 bb = *(const float4*)(bfv + c0 + j * 4);
    v[j * 4 + 0] = x.x + bq.x + bb.x;
    v[j * 4 + 1] = x.y + bq.y + bb.y;
    v[j * 4 + 2] = x.z + bq.z + bb.z;
    v[j * 4 + 3] = x.w + bq.w + bb.w;
#pragma unroll
    for (int e = 0; e < 4; ++e) { float w = v[j * 4 + e]; s += w; ss += w * w; }
  }
  s = wave_sum(s); ss = wave_sum(ss);
  __shared__ float rs[4], rss[4];
  if ((t & 63) == 0) { rs[t >> 6] = s; rss[t >> 6] = ss; }
  __syncthreads();
  const float S  = rs[0] + rs[1] + rs[2] + rs[3];
  const float SS = rss[0] + rss[1] + rss[2] + rss[3];
  const float mu   = S * (1.f / OD);
  const float var  = SS * (1.f / OD) - mu * mu;
  const float rstd = rsqrtf(var + 1e-5f);
#pragma unroll
  for (int j = 0; j < 2; ++j) {
    float4 g  = *(const float4*)(gamma + c0 + j * 4);
    float4 be = *(const float4*)(beta  + c0 + j * 4);
    float4 o;
    float xn;
    xn  = (v[j * 4 + 0] - mu) * rstd * g.x + be.x; o.x = 0.5f * xn * (1.f + erff(xn * 0.70710678118f));
    xn  = (v[j * 4 + 1] - mu) * rstd * g.y + be.y; o.y = 0.5f * xn * (1.f + erff(xn * 0.70710678118f));
    xn  = (v[j * 4 + 2] - mu) * rstd * g.z + be.z; o.z = 0.5f * xn * (1.f + erff(xn * 0.70710678118f));
    xn  = (v[j * 4 + 3] - mu) * rstd * g.w + be.w; o.w = 0.5f * xn * (1.f + erff(xn * 0.70710678118f));
    *(float4*)(out + (size_t)row * OD + c0 + j * 4) = o;
  }
}

extern "C" void kernel_launch(void* const* d_in, const int* in_sizes, int n_in,
                              void* d_out, int out_size, void* d_ws, size_t ws_size,
                              hipStream_t stream) {
  const float* x     = (const float*)d_in[0];   // [4,2048,2048]
  const float* W16   = (const float*)d_in[1];   // [16,2048,2048] == W16r [32768][2048]
  const float* b16   = (const float*)d_in[2];   // [16,2048] flat == b16flat[32768]
  const float* Wf    = (const float*)d_in[3];   // [2048][32768]
  const float* bfv   = (const float*)d_in[4];   // [2048]
  const float* gamma = (const float*)d_in[5];   // [2048]
  const float* beta  = (const float*)d_in[6];   // [2048]
  float* out = (float*)d_out;

  // workspace layout (total ~360 MiB)
  char* ws = (char*)d_ws;
  bf16_t* W16T  = (bf16_t*)(ws);                 // [2048][32768] bf16, 128 MiB
  bf16_t* Wf16  = (bf16_t*)(ws + 134217728);     // [2048][32768] bf16, 128 MiB
  bf16_t* X16   = (bf16_t*)(ws + 268435456);     // [8192][2048] bf16, 32 MiB
  bf16_t* Weq   = (bf16_t*)(ws + 301989888);     // [2048][2048] bf16, 8 MiB
  float*  beq   = (float*)(ws + 310378496);      // [2048] f32, 8 KiB
  float*  slabs = (float*)(ws + 310386688);      // 4 x [2048][2048] f32 = 64 MiB; reused as fused
  float*  fused = slabs;                         // [8192][2048] f32 (after reduce_weq)

  hipMemsetAsync(beq, 0, OD * sizeof(float), stream);

  conv_wf_beq<<<dim3(16, 2048), 256, 0, stream>>>(Wf, b16, Wf16, beq);
  transpose_w16<<<dim3(KC / 64, ID / 64), 256, 0, stream>>>(W16, W16T);
  conv_x<<<(BSROWS * ID) / (256 * 8), 256, 0, stream>>>(x, X16);

  // GEMM1: Weq = Wf16 [2048][32768] * W16T^T, K-split 4 -> slabs
  gemm_bt<<<dim3(ID / 128, OD / 128, 4), 256, 0, stream>>>(
      Wf16, W16T, slabs, OD, ID, KC, KC, KC / 4);
  reduce_weq<<<(OD * ID) / (256 * 4), 256, 0, stream>>>(slabs, Weq);

  // GEMM2: fused = X16 [8192][2048] * Weq^T [2048][2048]
  gemm_bt<<<dim3(OD / 128, BSROWS / 128, 1), 256, 0, stream>>>(
      X16, Weq, fused, BSROWS, OD, ID, ID, ID);

  ln_gelu<<<BSROWS, 256, 0, stream>>>(fused, beq, bfv, gamma, beta, out);
}

// Round 2
// 627.027 us; speedup vs baseline: 1.4041x; 1.4041x over previous
//
#include <hip/hip_runtime.h>
#include <hip/hip_bf16.h>
#include <math.h>

// QuantumNeuralLayer: collapsed to fused = x @ Weq^T + beq, Weq = Wf @ W16r.
// R2: 256^2-tile 8-wave GEMM with T1 xcd-swizzle, T2 st_16x32 LDS swizzle,
// T3/T4 counted-vmcnt 2-deep pipeline, T5 setprio.

typedef __bf16 bf16_t;
typedef __bf16 bf16x8 __attribute__((ext_vector_type(8)));
typedef __bf16 bf16x4 __attribute__((ext_vector_type(4)));
typedef float  f32x4  __attribute__((ext_vector_type(4)));

#define KC 32768
#define OD 2048
#define ID 2048
#define BSROWS 8192

#define GLL16(g, l) __builtin_amdgcn_global_load_lds( \
    (const __attribute__((address_space(1))) void*)(g), \
    (__attribute__((address_space(3))) void*)(l), 16, 0, 0)

__device__ __forceinline__ float wave_sum(float v) {
#pragma unroll
  for (int o = 32; o > 0; o >>= 1) v += __shfl_down(v, o, 64);
  return v;
}

// ---------------------------------------------------------------------------
// 256x256-tile GEMM: C[m][n] += A[m][k] * B[n][k]^T (bf16 in, f32 out)
// 512 threads = 8 waves (2M x 4N), BK=64, LDS 128 KiB (2 dbuf x (A 32K + B 32K))
// LDS swizzle: physical = logical ^ ((bit9)<<5)  (involution, st_16x32)
// ---------------------------------------------------------------------------

__device__ __forceinline__ void stage_all(const bf16_t* gA, const bf16_t* gB,
                                          int lda, int ldb,
                                          char* Ab, char* Bb, int wave) {
  // linear LDS dest (wave-uniform base + lane*16); source pre-swizzled per-lane
  char* da = Ab + wave * 1024;
  char* db = Bb + wave * 1024;
  GLL16(gA,                     da);
  GLL16(gA + (size_t)64 * lda,  da + 8192);
  GLL16(gA + (size_t)128 * lda, da + 16384);
  GLL16(gA + (size_t)192 * lda, da + 24576);
  GLL16(gB,                     db);
  GLL16(gB + (size_t)64 * ldb,  db + 8192);
  GLL16(gB + (size_t)128 * ldb, db + 16384);
  GLL16(gB + (size_t)192 * ldb, db + 24576);
}

__device__ __forceinline__ void read_b(const char* Bb, int wcbase, int frow, int fk16,
                                       bf16x8 (&bfr)[4][2]) {
#pragma unroll
  for (int n = 0; n < 4; ++n)
#pragma unroll
    for (int ks = 0; ks < 2; ++ks) {
      const int r = wcbase + n * 16 + frow;
      const int off = r * 128 + ((ks * 64 + fk16) ^ ((r & 4) << 3));
      bfr[n][ks] = *reinterpret_cast<const bf16x8*>(Bb + off);
    }
}

__device__ __forceinline__ void read_aq(const char* Ab, int wrbase, int frow, int fk16,
                                        int q, bf16x8 (&ar)[2][2]) {
#pragma unroll
  for (int mh = 0; mh < 2; ++mh)
#pragma unroll
    for (int ks = 0; ks < 2; ++ks) {
      const int r = wrbase + q * 32 + mh * 16 + frow;
      const int off = r * 128 + ((ks * 64 + fk16) ^ ((r & 4) << 3));
      ar[mh][ks] = *reinterpret_cast<const bf16x8*>(Ab + off);
    }
}

__device__ __forceinline__ void mfma_q(int q, const bf16x8 (&ar)[2][2],
                                       const bf16x8 (&bfr)[4][2], f32x4 (&acc)[8][4]) {
  __builtin_amdgcn_s_setprio(1);
#pragma unroll
  for (int mh = 0; mh < 2; ++mh)
#pragma unroll
    for (int n = 0; n < 4; ++n)
#pragma unroll
      for (int ks = 0; ks < 2; ++ks)
        acc[q * 2 + mh][n] = __builtin_amdgcn_mfma_f32_16x16x32_bf16(
            ar[mh][ks], bfr[n][ks], acc[q * 2 + mh][n], 0, 0, 0);
  __builtin_amdgcn_s_setprio(0);
}

__global__ __launch_bounds__(512, 2) void gemm256(
    const bf16_t* __restrict__ A, const bf16_t* __restrict__ B,
    float* __restrict__ C, int M, int N, int lda, int ldb,
    int Ks, int nbn, int mn)
{
  __shared__ char lds[131072];  // A0 @0, A1 @32768, B0 @65536, B1 @98304
  const int tid  = threadIdx.x;
  const int lane = tid & 63;
  const int wave = tid >> 6;

  // T1: bijective XCD swizzle (gridDim.x % 8 == 0 in all launches)
  const int nwg = gridDim.x;
  const int per = nwg >> 3;
  const int swz = (blockIdx.x & 7) * per + (blockIdx.x >> 3);
  const int z   = swz / mn;
  const int rem = swz - z * mn;
  const int bm  = (rem / nbn) * 256;
  const int bn  = (rem % nbn) * 256;
  const int k0  = z * Ks;
  float* Cz = C + (size_t)z * ((size_t)M * (size_t)N);

  const int wr = wave >> 2, wc = wave & 3;
  const int wrbase = wr * 128, wcbase = wc * 64;
  const int frow = lane & 15;
  const int fk16 = (lane >> 4) * 16;

  // T2 staging source pre-swizzle: flips bit1 of the 16B-slot index when bit5 set
  const int ts   = tid ^ (((tid >> 5) & 1) << 1);
  const int srow = ts >> 3;
  const int scol = (ts & 7) * 8;
  const bf16_t* gAs = A + (size_t)(bm + srow) * lda + k0 + scol;
  const bf16_t* gBs = B + (size_t)(bn + srow) * ldb + k0 + scol;

  f32x4 acc[8][4] = {};
  bf16x8 a0[2][2], a1[2][2], bfr[4][2];

  const int NT = Ks >> 6;

  // prologue: stage K-tiles 0 and 1
  stage_all(gAs, gBs, lda, ldb, lds,         lds + 65536, wave); gAs += 64; gBs += 64;
  stage_all(gAs, gBs, lda, ldb, lds + 32768, lds + 98304, wave); gAs += 64; gBs += 64;
  asm volatile("s_waitcnt vmcnt(8)" ::: "memory");   // tile 0 landed, tile 1 in flight
  __builtin_amdgcn_s_barrier();
  read_b(lds + 65536, wcbase, frow, fk16, bfr);
  read_aq(lds, wrbase, frow, fk16, 0, a0);

#pragma unroll 1
  for (int t = 0; t < NT; ++t) {
    const int cur = t & 1;
    char* Ab = lds + (cur << 15);
    char* Bb = lds + 65536 + (cur << 15);

    // 4 quadrant phases: ds_read next quadrant || 16 MFMA on current regs
    read_aq(Ab, wrbase, frow, fk16, 1, a1);  mfma_q(0, a0, bfr, acc);
    read_aq(Ab, wrbase, frow, fk16, 2, a0);  mfma_q(1, a1, bfr, acc);
    read_aq(Ab, wrbase, frow, fk16, 3, a1);  mfma_q(2, a0, bfr, acc);
                                             mfma_q(3, a1, bfr, acc);
    // all this wave's ds_reads of buf[cur] retired (MFMA operand deps)
    __builtin_amdgcn_s_barrier();            // all waves done with buf[cur]
    if (t + 2 < NT) {
      stage_all(gAs, gBs, lda, ldb, Ab, Bb, wave);  gAs += 64; gBs += 64;
      asm volatile("s_waitcnt vmcnt(8)" ::: "memory");  // tile t+1 landed; t+2 in flight
    } else {
      asm volatile("s_waitcnt vmcnt(0)" ::: "memory");  // tail drain
    }
    __builtin_amdgcn_s_barrier();            // all waves' t+1 loads retired
    if (t + 1 < NT) {                        // preload next tile's B-frags + A-q0
      const char* An = lds + ((cur ^ 1) << 15);
      const char* Bn = lds + 65536 + ((cur ^ 1) << 15);
      read_b(Bn, wcbase, frow, fk16, bfr);
      read_aq(An, wrbase, frow, fk16, 0, a0);
    }
  }

  // C/D layout: col = lane&15, row = (lane>>4)*4 + j
  const int cr = (lane >> 4) * 4, cc = lane & 15;
#pragma unroll
  for (int m = 0; m < 8; ++m)
#pragma unroll
    for (int n = 0; n < 4; ++n) {
      size_t base = (size_t)(bm + wrbase + m * 16 + cr) * N + (bn + wcbase + n * 16 + cc);
#pragma unroll
      for (int j = 0; j < 4; ++j)
        Cz[base + (size_t)j * N] = acc[m][n][j];
    }
}

// ---------------- Wf f32 -> bf16, and beq partial = sum_c b16[c]*Wf[o,c] ----------
__global__ void conv_wf_beq(const float* __restrict__ Wf, const float* __restrict__ b16,
                            bf16_t* __restrict__ Wf16, float* __restrict__ beq)
{
  const int o  = blockIdx.y;
  const int cb = blockIdx.x * 2048;
  const int t  = threadIdx.x;
  const size_t gbase = (size_t)o * KC + cb + t * 8;
  const float4 v0 = *(const float4*)(Wf + gbase);
  const float4 v1 = *(const float4*)(Wf + gbase + 4);
  const float4 b0 = *(const float4*)(b16 + cb + t * 8);
  const float4 b1 = *(const float4*)(b16 + cb + t * 8 + 4);
  bf16x8 r;
  r[0] = (bf16_t)v0.x; r[1] = (bf16_t)v0.y; r[2] = (bf16_t)v0.z; r[3] = (bf16_t)v0.w;
  r[4] = (bf16_t)v1.x; r[5] = (bf16_t)v1.y; r[6] = (bf16_t)v1.z; r[7] = (bf16_t)v1.w;
  *reinterpret_cast<bf16x8*>(Wf16 + gbase) = r;
  float s = v0.x * b0.x + v0.y * b0.y + v0.z * b0.z + v0.w * b0.w
          + v1.x * b1.x + v1.y * b1.y + v1.z * b1.z + v1.w * b1.w;
  s = wave_sum(s);
  __shared__ float red[4];
  if ((t & 63) == 0) red[t >> 6] = s;
  __syncthreads();
  if (t == 0) atomicAdd(beq + o, red[0] + red[1] + red[2] + red[3]);
}

// ---------------- W16 [c][i] f32 -> W16T [i][c] bf16 ------------------------------
__global__ void transpose_w16(const float* __restrict__ W, bf16_t* __restrict__ T)
{
  __shared__ bf16_t tile[64][65];
  const int cb = blockIdx.x * 64;
  const int ib = blockIdx.y * 64;
  const int tx = threadIdx.x & 63;
  const int ty = threadIdx.x >> 6;
#pragma unroll
  for (int r = ty; r < 64; r += 4)
    tile[r][tx] = (bf16_t)W[(size_t)(cb + r) * ID + ib + tx];
  __syncthreads();
#pragma unroll
  for (int r = ty; r < 64; r += 4)
    T[(size_t)(ib + r) * KC + cb + tx] = tile[tx][r];
}

// ---------------- x f32 -> bf16 ---------------------------------------------------
__global__ void conv_x(const float* __restrict__ X, bf16_t* __restrict__ X16)
{
  const size_t i = ((size_t)blockIdx.x * 256 + threadIdx.x) * 8;
  const float4 v0 = *(const float4*)(X + i);
  const float4 v1 = *(const float4*)(X + i + 4);
  bf16x8 r;
  r[0] = (bf16_t)v0.x; r[1] = (bf16_t)v0.y; r[2] = (bf16_t)v0.z; r[3] = (bf16_t)v0.w;
  r[4] = (bf16_t)v1.x; r[5] = (bf16_t)v1.y; r[6] = (bf16_t)v1.z; r[7] = (bf16_t)v1.w;
  *reinterpret_cast<bf16x8*>(X16 + i) = r;
}

// ---------------- reduce 4 K-split slabs -> Weq bf16 ------------------------------
__global__ void reduce_weq(const float* __restrict__ slabs, bf16_t* __restrict__ Weq)
{
  const size_t MN = (size_t)OD * ID;
  const size_t i = ((size_t)blockIdx.x * 256 + threadIdx.x) * 4;
  float4 a = *(const float4*)(slabs + i);
  float4 b = *(const float4*)(slabs + MN + i);
  float4 c = *(const float4*)(slabs + 2 * MN + i);
  float4 d = *(const float4*)(slabs + 3 * MN + i);
  bf16x4 r;
  r[0] = (bf16_t)(a.x + b.x + c.x + d.x);
  r[1] = (bf16_t)(a.y + b.y + c.y + d.y);
  r[2] = (bf16_t)(a.z + b.z + c.z + d.z);
  r[3] = (bf16_t)(a.w + b.w + c.w + d.w);
  *reinterpret_cast<bf16x4*>(Weq + i) = r;
}

// ---------------- bias + LayerNorm + exact GELU -----------------------------------
__global__ __launch_bounds__(256) void ln_gelu(
    const float* __restrict__ fused, const float* __restrict__ beq,
    const float* __restrict__ bfv, const float* __restrict__ gamma,
    const float* __restrict__ beta, float* __restrict__ out)
{
  const int row = blockIdx.x;
  const int t = threadIdx.x;
  const float* fr = fused + (size_t)row * OD;
  const int c0 = t * 8;
  float v[8];
  float s = 0.f, ss = 0.f;
#pragma unroll
  for (int j = 0; j < 2; ++j) {
    float4 x  = *(const float4*)(fr  + c0 + j * 4);
    float4 bq = *(const float4*)(beq + c0 + j * 4);
    float4 bb = *(const float4*)(bfv + c0 + j * 4);
    v[j * 4 + 0] = x.x + bq.x + bb.x;
    v[j * 4 + 1] = x.y + bq.y + bb.y;
    v[j * 4 + 2] = x.z + bq.z + bb.z;
    v[j * 4 + 3] = x.w + bq.w + bb.w;
#pragma unroll
    for (int e = 0; e < 4; ++e) { float w = v[j * 4 + e]; s += w; ss += w * w; }
  }
  s = wave_sum(s); ss = wave_sum(ss);
  __shared__ float rs[4], rss[4];
  if ((t & 63) == 0) { rs[t >> 6] = s; rss[t >> 6] = ss; }
  __syncthreads();
  const float S  = rs[0] + rs[1] + rs[2] + rs[3];
  const float SS = rss[0] + rss[1] + rss[2] + rss[3];
  const float mu   = S * (1.f / OD);
  const float var  = SS * (1.f / OD) - mu * mu;
  const float rstd = rsqrtf(var + 1e-5f);
#pragma unroll
  for (int j = 0; j < 2; ++j) {
    float4 g  = *(const float4*)(gamma + c0 + j * 4);
    float4 be = *(const float4*)(beta  + c0 + j * 4);
    float4 o;
    float xn;
    xn  = (v[j * 4 + 0] - mu) * rstd * g.x + be.x; o.x = 0.5f * xn * (1.f + erff(xn * 0.70710678118f));
    xn  = (v[j * 4 + 1] - mu) * rstd * g.y + be.y; o.y = 0.5f * xn * (1.f + erff(xn * 0.70710678118f));
    xn  = (v[j * 4 + 2] - mu) * rstd * g.z + be.z; o.z = 0.5f * xn * (1.f + erff(xn * 0.70710678118f));
    xn  = (v[j * 4 + 3] - mu) * rstd * g.w + be.w; o.w = 0.5f * xn * (1.f + erff(xn * 0.70710678118f));
    *(float4*)(out + (size_t)row * OD + c0 + j * 4) = o;
  }
}

extern "C" void kernel_launch(void* const* d_in, const int* in_sizes, int n_in,
                              void* d_out, int out_size, void* d_ws, size_t ws_size,
                              hipStream_t stream) {
  const float* x     = (const float*)d_in[0];
  const float* W16   = (const float*)d_in[1];
  const float* b16   = (const float*)d_in[2];
  const float* Wf    = (const float*)d_in[3];
  const float* bfv   = (const float*)d_in[4];
  const float* gamma = (const float*)d_in[5];
  const float* beta  = (const float*)d_in[6];
  float* out = (float*)d_out;

  char* ws = (char*)d_ws;
  bf16_t* W16T  = (bf16_t*)(ws);                 // [2048][32768] bf16, 128 MiB
  bf16_t* Wf16  = (bf16_t*)(ws + 134217728);     // [2048][32768] bf16, 128 MiB
  bf16_t* X16   = (bf16_t*)(ws + 268435456);     // [8192][2048] bf16, 32 MiB
  bf16_t* Weq   = (bf16_t*)(ws + 301989888);     // [2048][2048] bf16, 8 MiB
  float*  beq   = (float*)(ws + 310378496);      // [2048] f32
  float*  slabs = (float*)(ws + 310386688);      // 4 x 16 MiB f32; reused as fused
  float*  fused = slabs;

  hipMemsetAsync(beq, 0, OD * sizeof(float), stream);

  conv_wf_beq<<<dim3(16, 2048), 256, 0, stream>>>(Wf, b16, Wf16, beq);
  transpose_w16<<<dim3(KC / 64, ID / 64), 256, 0, stream>>>(W16, W16T);
  conv_x<<<(BSROWS * ID) / (256 * 8), 256, 0, stream>>>(x, X16);

  // GEMM1: Weq = Wf16 [2048][32768] * W16T^T, K-split 4 -> slabs
  // grid = 8(n) x 8(m) x 4(z) = 256 blocks, 1 per CU
  gemm256<<<256, 512, 0, stream>>>(Wf16, W16T, slabs, OD, ID, KC, KC, KC / 4, 8, 64);
  reduce_weq<<<(OD * ID) / (256 * 4), 256, 0, stream>>>(slabs, Weq);

  // GEMM2: fused = X16 [8192][2048] * Weq^T [2048][2048]; grid 32x8 = 256 blocks
  gemm256<<<256, 512, 0, stream>>>(X16, Weq, fused, BSROWS, OD, ID, ID, ID, 8, 256);

  ln_gelu<<<BSROWS, 256, 0, stream>>>(fused, beq, bfv, gamma, beta, out);
}

// Round 3
// 623.674 us; speedup vs baseline: 1.4117x; 1.0054x over previous
//
#include <hip/hip_runtime.h>
#include <hip/hip_bf16.h>
#include <math.h>

// QuantumNeuralLayer collapsed: fused = x @ Weq^T + beq, Weq = Wf @ W16r.
// R3 GEMM: 256x256 tile, K=32 chunks in a ring-4 LDS pipeline (128 KiB),
// natural conflict-free layout (64B rows), counted vmcnt, 1 barrier/chunk.

typedef __bf16 bf16_t;
typedef __bf16 bf16x8 __attribute__((ext_vector_type(8)));
typedef __bf16 bf16x4 __attribute__((ext_vector_type(4)));
typedef float  f32x4  __attribute__((ext_vector_type(4)));

#define KC 32768
#define OD 2048
#define ID 2048
#define BSROWS 8192

#define GLL16(g, l) __builtin_amdgcn_global_load_lds( \
    (const __attribute__((address_space(1))) void*)(g), \
    (__attribute__((address_space(3))) void*)(l), 16, 0, 0)

__device__ __forceinline__ float wave_sum(float v) {
#pragma unroll
  for (int o = 32; o > 0; o >>= 1) v += __shfl_down(v, o, 64);
  return v;
}

// ---------------------------------------------------------------------------
// C[m][n] (f32) = A[m][k] * B[n][k]^T, bf16 in. 512 thr = 8 waves (2M x 4N),
// per-wave output 128x64. Chunk = 256 rows x 32 k x 2B = 16 KiB per operand.
// Ring-4: buf i at lds + i*32768 (A), +16384 (B). Conflict-free by layout:
// bank = 16*(row&1) + 4*(lane>>4) + w  -> all 32 banks, 8 words each.
// ---------------------------------------------------------------------------
__global__ __launch_bounds__(512, 1) void gemm256(
    const bf16_t* __restrict__ A, const bf16_t* __restrict__ B,
    float* __restrict__ C, int M, int N, int lda, int ldb,
    int Ks, int nbn, int mn)
{
  __shared__ char lds[131072];
  const int tid  = threadIdx.x;
  const int lane = tid & 63;
  const int wave = tid >> 6;

  // T1: bijective XCD swizzle (gridDim.x % 8 == 0 in all launches)
  const int nwg = gridDim.x;
  const int per = nwg >> 3;
  const int swz = (blockIdx.x & 7) * per + (blockIdx.x >> 3);
  const int z   = swz / mn;
  const int rem = swz - z * mn;
  const int bm  = (rem / nbn) * 256;
  const int bn  = (rem % nbn) * 256;
  const int k0  = z * Ks;
  float* Cz = C + (size_t)z * ((size_t)M * (size_t)N);

  const int wr = wave >> 2, wc = wave & 3;
  const int wrbase = wr * 128, wcbase = wc * 64;
  const int frow   = lane & 15;
  const int slot16 = (lane >> 4) * 16;

  // staging: thread covers row tid>>2 (and +128), 8 elems at k-off (tid&3)*8
  const int srow = tid >> 2;
  const int scol = (tid & 3) * 8;
  const bf16_t* gA = A + (size_t)(bm + srow) * lda + k0 + scol;
  const bf16_t* gB = B + (size_t)(bn + srow) * ldb + k0 + scol;
  const int ldst = wave * 1024;            // wave-uniform LDS base (+lane*16)

  f32x4 acc[8][4] = {};
  const int NC = Ks >> 5;                  // K=32 chunks

#define STAGE(c) do {                                             \
    char* Ab_ = lds + (((c) & 3) << 15);                          \
    char* Bb_ = Ab_ + 16384;                                      \
    const bf16_t* a_ = gA + (c) * 32;                             \
    const bf16_t* b_ = gB + (c) * 32;                             \
    GLL16(a_,                     Ab_ + ldst);                    \
    GLL16(a_ + (size_t)128 * lda, Ab_ + 8192 + ldst);             \
    GLL16(b_,                     Bb_ + ldst);                    \
    GLL16(b_ + (size_t)128 * ldb, Bb_ + 8192 + ldst);             \
  } while (0)

  STAGE(0); STAGE(1); STAGE(2);

  const int aoff = (wrbase + frow) * 64 + slot16;
  const int boff = (wcbase + frow) * 64 + slot16;

#pragma unroll 1
  for (int c = 0; c < NC; ++c) {
    // chunk c landed: outstanding <= {c+1, c+2} afterwards (counted, never 0 mid-loop)
    if (c < NC - 2)       asm volatile("s_waitcnt vmcnt(8)" ::: "memory");
    else if (c == NC - 2) asm volatile("s_waitcnt vmcnt(4)" ::: "memory");
    else                  asm volatile("s_waitcnt vmcnt(0)" ::: "memory");
    __builtin_amdgcn_s_barrier();  // all waves: c landed, c-1 reads drained

    const char* ap = lds + ((c & 3) << 15) + aoff;
    const char* bp = lds + ((c & 3) << 15) + 16384 + boff;
    bf16x8 af[8], bg[4];
#pragma unroll
    for (int n = 0; n < 4; ++n)
      bg[n] = *reinterpret_cast<const bf16x8*>(bp + n * 1024);
#pragma unroll
    for (int m = 0; m < 8; ++m)
      af[m] = *reinterpret_cast<const bf16x8*>(ap + m * 1024);

    if (c + 3 < NC) STAGE(c + 3);   // overwrites buf of c-1 (drained at barrier)

    __builtin_amdgcn_s_setprio(1);
#pragma unroll
    for (int m = 0; m < 8; ++m)
#pragma unroll
      for (int n = 0; n < 4; ++n)
        acc[m][n] = __builtin_amdgcn_mfma_f32_16x16x32_bf16(af[m], bg[n], acc[m][n], 0, 0, 0);
    __builtin_amdgcn_s_setprio(0);
  }
#undef STAGE

  // C/D layout (m89-verified): col = lane&15, row = (lane>>4)*4 + j
  const int cr = (lane >> 4) * 4, cc = lane & 15;
#pragma unroll
  for (int m = 0; m < 8; ++m)
#pragma unroll
    for (int n = 0; n < 4; ++n) {
      size_t base = (size_t)(bm + wrbase + m * 16 + cr) * N + (bn + wcbase + n * 16 + cc);
#pragma unroll
      for (int j = 0; j < 4; ++j)
        Cz[base + (size_t)j * N] = acc[m][n][j];
    }
}

// ---------------- Wf f32 -> bf16, and beq partial = sum_c b16[c]*Wf[o,c] ----------
__global__ void conv_wf_beq(const float* __restrict__ Wf, const float* __restrict__ b16,
                            bf16_t* __restrict__ Wf16, float* __restrict__ beq)
{
  const int o  = blockIdx.y;
  const int cb = blockIdx.x * 2048;
  const int t  = threadIdx.x;
  const size_t gbase = (size_t)o * KC + cb + t * 8;
  const float4 v0 = *(const float4*)(Wf + gbase);
  const float4 v1 = *(const float4*)(Wf + gbase + 4);
  const float4 b0 = *(const float4*)(b16 + cb + t * 8);
  const float4 b1 = *(const float4*)(b16 + cb + t * 8 + 4);
  bf16x8 r;
  r[0] = (bf16_t)v0.x; r[1] = (bf16_t)v0.y; r[2] = (bf16_t)v0.z; r[3] = (bf16_t)v0.w;
  r[4] = (bf16_t)v1.x; r[5] = (bf16_t)v1.y; r[6] = (bf16_t)v1.z; r[7] = (bf16_t)v1.w;
  *reinterpret_cast<bf16x8*>(Wf16 + gbase) = r;
  float s = v0.x * b0.x + v0.y * b0.y + v0.z * b0.z + v0.w * b0.w
          + v1.x * b1.x + v1.y * b1.y + v1.z * b1.z + v1.w * b1.w;
  s = wave_sum(s);
  __shared__ float red[4];
  if ((t & 63) == 0) red[t >> 6] = s;
  __syncthreads();
  if (t == 0) atomicAdd(beq + o, red[0] + red[1] + red[2] + red[3]);
}

// ---------------- W16 [c][i] f32 -> W16T [i][c] bf16 ------------------------------
__global__ void transpose_w16(const float* __restrict__ W, bf16_t* __restrict__ T)
{
  __shared__ bf16_t tile[64][65];
  const int cb = blockIdx.x * 64;
  const int ib = blockIdx.y * 64;
  const int tx = threadIdx.x & 63;
  const int ty = threadIdx.x >> 6;
#pragma unroll
  for (int r = ty; r < 64; r += 4)
    tile[r][tx] = (bf16_t)W[(size_t)(cb + r) * ID + ib + tx];
  __syncthreads();
#pragma unroll
  for (int r = ty; r < 64; r += 4)
    T[(size_t)(ib + r) * KC + cb + tx] = tile[tx][r];
}

// ---------------- x f32 -> bf16 ---------------------------------------------------
__global__ void conv_x(const float* __restrict__ X, bf16_t* __restrict__ X16)
{
  const size_t i = ((size_t)blockIdx.x * 256 + threadIdx.x) * 8;
  const float4 v0 = *(const float4*)(X + i);
  const float4 v1 = *(const float4*)(X + i + 4);
  bf16x8 r;
  r[0] = (bf16_t)v0.x; r[1] = (bf16_t)v0.y; r[2] = (bf16_t)v0.z; r[3] = (bf16_t)v0.w;
  r[4] = (bf16_t)v1.x; r[5] = (bf16_t)v1.y; r[6] = (bf16_t)v1.z; r[7] = (bf16_t)v1.w;
  *reinterpret_cast<bf16x8*>(X16 + i) = r;
}

// ---------------- reduce 4 K-split slabs -> Weq bf16 ------------------------------
__global__ void reduce_weq(const float* __restrict__ slabs, bf16_t* __restrict__ Weq)
{
  const size_t MN = (size_t)OD * ID;
  const size_t i = ((size_t)blockIdx.x * 256 + threadIdx.x) * 4;
  float4 a = *(const float4*)(slabs + i);
  float4 b = *(const float4*)(slabs + MN + i);
  float4 c = *(const float4*)(slabs + 2 * MN + i);
  float4 d = *(const float4*)(slabs + 3 * MN + i);
  bf16x4 r;
  r[0] = (bf16_t)(a.x + b.x + c.x + d.x);
  r[1] = (bf16_t)(a.y + b.y + c.y + d.y);
  r[2] = (bf16_t)(a.z + b.z + c.z + d.z);
  r[3] = (bf16_t)(a.w + b.w + c.w + d.w);
  *reinterpret_cast<bf16x4*>(Weq + i) = r;
}

// ---------------- bias + LayerNorm + exact GELU -----------------------------------
__global__ __launch_bounds__(256) void ln_gelu(
    const float* __restrict__ fused, const float* __restrict__ beq,
    const float* __restrict__ bfv, const float* __restrict__ gamma,
    const float* __restrict__ beta, float* __restrict__ out)
{
  const int row = blockIdx.x;
  const int t = threadIdx.x;
  const float* fr = fused + (size_t)row * OD;
  const int c0 = t * 8;
  float v[8];
  float s = 0.f, ss = 0.f;
#pragma unroll
  for (int j = 0; j < 2; ++j) {
    float4 x  = *(const float4*)(fr  + c0 + j * 4);
    float4 bq = *(const float4*)(beq + c0 + j * 4);
    float4 bb = *(const float4*)(bfv + c0 + j * 4);
    v[j * 4 + 0] = x.x + bq.x + bb.x;
    v[j * 4 + 1] = x.y + bq.y + bb.y;
    v[j * 4 + 2] = x.z + bq.z + bb.z;
    v[j * 4 + 3] = x.w + bq.w + bb.w;
#pragma unroll
    for (int e = 0; e < 4; ++e) { float w = v[j * 4 + e]; s += w; ss += w * w; }
  }
  s = wave_sum(s); ss = wave_sum(ss);
  __shared__ float rs[4], rss[4];
  if ((t & 63) == 0) { rs[t >> 6] = s; rss[t >> 6] = ss; }
  __syncthreads();
  const float S  = rs[0] + rs[1] + rs[2] + rs[3];
  const float SS = rss[0] + rss[1] + rss[2] + rss[3];
  const float mu   = S * (1.f / OD);
  const float var  = SS * (1.f / OD) - mu * mu;
  const float rstd = rsqrtf(var + 1e-5f);
#pragma unroll
  for (int j = 0; j < 2; ++j) {
    float4 g  = *(const float4*)(gamma + c0 + j * 4);
    float4 be = *(const float4*)(beta  + c0 + j * 4);
    float4 o;
    float xn;
    xn  = (v[j * 4 + 0] - mu) * rstd * g.x + be.x; o.x = 0.5f * xn * (1.f + erff(xn * 0.70710678118f));
    xn  = (v[j * 4 + 1] - mu) * rstd * g.y + be.y; o.y = 0.5f * xn * (1.f + erff(xn * 0.70710678118f));
    xn  = (v[j * 4 + 2] - mu) * rstd * g.z + be.z; o.z = 0.5f * xn * (1.f + erff(xn * 0.70710678118f));
    xn  = (v[j * 4 + 3] - mu) * rstd * g.w + be.w; o.w = 0.5f * xn * (1.f + erff(xn * 0.70710678118f));
    *(float4*)(out + (size_t)row * OD + c0 + j * 4) = o;
  }
}

extern "C" void kernel_launch(void* const* d_in, const int* in_sizes, int n_in,
                              void* d_out, int out_size, void* d_ws, size_t ws_size,
                              hipStream_t stream) {
  const float* x     = (const float*)d_in[0];
  const float* W16   = (const float*)d_in[1];
  const float* b16   = (const float*)d_in[2];
  const float* Wf    = (const float*)d_in[3];
  const float* bfv   = (const float*)d_in[4];
  const float* gamma = (const float*)d_in[5];
  const float* beta  = (const float*)d_in[6];
  float* out = (float*)d_out;

  char* ws = (char*)d_ws;
  bf16_t* W16T  = (bf16_t*)(ws);                 // [2048][32768] bf16, 128 MiB
  bf16_t* Wf16  = (bf16_t*)(ws + 134217728);     // [2048][32768] bf16, 128 MiB
  bf16_t* X16   = (bf16_t*)(ws + 268435456);     // [8192][2048] bf16, 32 MiB
  bf16_t* Weq   = (bf16_t*)(ws + 301989888);     // [2048][2048] bf16, 8 MiB
  float*  beq   = (float*)(ws + 310378496);      // [2048] f32
  float*  slabs = (float*)(ws + 310386688);      // 4 x 16 MiB f32; reused as fused
  float*  fused = slabs;

  hipMemsetAsync(beq, 0, OD * sizeof(float), stream);

  conv_wf_beq<<<dim3(16, 2048), 256, 0, stream>>>(Wf, b16, Wf16, beq);
  transpose_w16<<<dim3(KC / 64, ID / 64), 256, 0, stream>>>(W16, W16T);
  conv_x<<<(BSROWS * ID) / (256 * 8), 256, 0, stream>>>(x, X16);

  // GEMM1: Weq = Wf16 [2048][32768] * W16T^T, K-split 4 -> slabs (grid 256)
  gemm256<<<256, 512, 0, stream>>>(Wf16, W16T, slabs, OD, ID, KC, KC, KC / 4, 8, 64);
  reduce_weq<<<(OD * ID) / (256 * 4), 256, 0, stream>>>(slabs, Weq);

  // GEMM2: fused = X16 [8192][2048] * Weq^T [2048][2048] (grid 32x8 = 256)
  gemm256<<<256, 512, 0, stream>>>(X16, Weq, fused, BSROWS, OD, ID, ID, ID, 8, 256);

  ln_gelu<<<BSROWS, 256, 0, stream>>>(fused, beq, bfv, gamma, beta, out);
}

// Round 4
// 600.344 us; speedup vs baseline: 1.4666x; 1.0389x over previous
//
#include <hip/hip_runtime.h>
#include <hip/hip_bf16.h>
#include <math.h>

// QuantumNeuralLayer collapsed: fused = x @ Weq^T + beq, Weq = Wf @ W16r.
// R4 GEMM: 256x256 tile, K=32 chunks, ring-4 LDS + register read-ahead:
// phase c = {vmcnt(8); barrier; stage(c+4); ds_read(c+1)->regs; MFMA(c)}.
// MFMA never reads LDS in its own phase; vmcnt stays counted (never 0 mid-loop).

typedef __bf16 bf16_t;
typedef __bf16 bf16x8 __attribute__((ext_vector_type(8)));
typedef __bf16 bf16x4 __attribute__((ext_vector_type(4)));
typedef float  f32x4  __attribute__((ext_vector_type(4)));

#define KC 32768
#define OD 2048
#define ID 2048
#define BSROWS 8192

#define GLL16(g, l) __builtin_amdgcn_global_load_lds( \
    (const __attribute__((address_space(1))) void*)(g), \
    (__attribute__((address_space(3))) void*)(l), 16, 0, 0)

__device__ __forceinline__ float wave_sum(float v) {
#pragma unroll
  for (int o = 32; o > 0; o >>= 1) v += __shfl_down(v, o, 64);
  return v;
}

__global__ __launch_bounds__(512, 1) void gemm256(
    const bf16_t* __restrict__ A, const bf16_t* __restrict__ B,
    float* __restrict__ C, int M, int N, int lda, int ldb,
    int Ks, int nbn, int mn)
{
  __shared__ char lds[131072];   // ring-4 slots: slot s at s*32768 (A 16K + B 16K)
  const int tid  = threadIdx.x;
  const int lane = tid & 63;
  const int wave = tid >> 6;

  // T1: bijective XCD swizzle (gridDim.x % 8 == 0)
  const int nwg = gridDim.x;
  const int per = nwg >> 3;
  const int swz = (blockIdx.x & 7) * per + (blockIdx.x >> 3);
  const int z   = swz / mn;
  const int rem = swz - z * mn;
  const int bm  = (rem / nbn) * 256;
  const int bn  = (rem % nbn) * 256;
  const int k0  = z * Ks;
  float* Cz = C + (size_t)z * ((size_t)M * (size_t)N);

  const int wr = wave >> 2, wc = wave & 3;
  const int wrbase = wr * 128, wcbase = wc * 64;
  const int frow   = lane & 15;
  const int slot16 = (lane >> 4) * 16;

  // staging: thread covers row tid>>2 (and +128), 16B at k-off (tid&3)*8
  const int srow = tid >> 2;
  const int scol = (tid & 3) * 8;
  const bf16_t* gA = A + (size_t)(bm + srow) * lda + k0 + scol;
  const bf16_t* gB = B + (size_t)(bn + srow) * ldb + k0 + scol;
  const int ldst = wave * 1024;  // + lane*16 implied by global_load_lds

  f32x4 acc[8][4] = {};
  bf16x8 afA[8], bgA[4], afB[8], bgB[4];
  const int NC = Ks >> 5;        // number of K=32 chunks (>= 8, even)

  const int aoff = (wrbase + frow) * 64 + slot16;
  const int boff = (wcbase + frow) * 64 + slot16;

#define STAGE(c) do {                                             \
    char* Ab_ = lds + (((c) & 3) << 15);                          \
    char* Bb_ = Ab_ + 16384;                                      \
    const bf16_t* a_ = gA + (size_t)(c) * 32;                     \
    const bf16_t* b_ = gB + (size_t)(c) * 32;                     \
    GLL16(a_,                     Ab_ + ldst);                    \
    GLL16(a_ + (size_t)128 * lda, Ab_ + 8192 + ldst);             \
    GLL16(b_,                     Bb_ + ldst);                    \
    GLL16(b_ + (size_t)128 * ldb, Bb_ + 8192 + ldst);             \
  } while (0)

#define READ(c, af, bg) do {                                      \
    const char* ap_ = lds + (((c) & 3) << 15) + aoff;             \
    const char* bp_ = lds + (((c) & 3) << 15) + 16384 + boff;     \
    _Pragma("unroll")                                             \
    for (int n = 0; n < 4; ++n)                                   \
      bg[n] = *reinterpret_cast<const bf16x8*>(bp_ + n * 1024);   \
    _Pragma("unroll")                                             \
    for (int m = 0; m < 8; ++m)                                   \
      af[m] = *reinterpret_cast<const bf16x8*>(ap_ + m * 1024);   \
  } while (0)

#define MFMA32(af, bg) do {                                       \
    __builtin_amdgcn_s_setprio(1);                                \
    _Pragma("unroll")                                             \
    for (int m = 0; m < 8; ++m)                                   \
      _Pragma("unroll")                                           \
      for (int n = 0; n < 4; ++n)                                 \
        acc[m][n] = __builtin_amdgcn_mfma_f32_16x16x32_bf16(      \
            af[m], bg[n], acc[m][n], 0, 0, 0);                    \
    __builtin_amdgcn_s_setprio(0);                                \
  } while (0)

  // phase c body: MFMA chunk c on `cur` regs; read chunk c+1 into `nxt` regs.
#define PHASE(c, afC, bgC, afN, bgN) do {                         \
    if ((c) < NC - 3)       asm volatile("s_waitcnt vmcnt(8)" ::: "memory"); \
    else if ((c) == NC - 3) asm volatile("s_waitcnt vmcnt(4)" ::: "memory"); \
    else if ((c) == NC - 2) asm volatile("s_waitcnt vmcnt(0)" ::: "memory"); \
    __builtin_amdgcn_s_barrier();                                 \
    if ((c) + 4 < NC) STAGE((c) + 4);                             \
    if ((c) + 1 < NC) READ((c) + 1, afN, bgN);                    \
    MFMA32(afC, bgC);                                             \
  } while (0)

  // prologue: stage chunks 0-3, wait chunk 0 landed, read it
  STAGE(0); STAGE(1); STAGE(2); STAGE(3);
  asm volatile("s_waitcnt vmcnt(12)" ::: "memory");
  __builtin_amdgcn_s_barrier();
  READ(0, afA, bgA);

#pragma unroll 1
  for (int c = 0; c < NC; c += 2) {
    PHASE(c,     afA, bgA, afB, bgB);
    PHASE(c + 1, afB, bgB, afA, bgA);
  }
#undef PHASE
#undef MFMA32
#undef READ
#undef STAGE

  // C/D layout (m89-verified): col = lane&15, row = (lane>>4)*4 + j
  const int cr = (lane >> 4) * 4, cc = lane & 15;
#pragma unroll
  for (int m = 0; m < 8; ++m)
#pragma unroll
    for (int n = 0; n < 4; ++n) {
      size_t base = (size_t)(bm + wrbase + m * 16 + cr) * N + (bn + wcbase + n * 16 + cc);
#pragma unroll
      for (int j = 0; j < 4; ++j)
        Cz[base + (size_t)j * N] = acc[m][n][j];
    }
}

// ---------------- Wf f32 -> bf16, and beq partial = sum_c b16[c]*Wf[o,c] ----------
__global__ void conv_wf_beq(const float* __restrict__ Wf, const float* __restrict__ b16,
                            bf16_t* __restrict__ Wf16, float* __restrict__ beq)
{
  const int o  = blockIdx.y;
  const int cb = blockIdx.x * 2048;
  const int t  = threadIdx.x;
  const size_t gbase = (size_t)o * KC + cb + t * 8;
  const float4 v0 = *(const float4*)(Wf + gbase);
  const float4 v1 = *(const float4*)(Wf + gbase + 4);
  const float4 b0 = *(const float4*)(b16 + cb + t * 8);
  const float4 b1 = *(const float4*)(b16 + cb + t * 8 + 4);
  bf16x8 r;
  r[0] = (bf16_t)v0.x; r[1] = (bf16_t)v0.y; r[2] = (bf16_t)v0.z; r[3] = (bf16_t)v0.w;
  r[4] = (bf16_t)v1.x; r[5] = (bf16_t)v1.y; r[6] = (bf16_t)v1.z; r[7] = (bf16_t)v1.w;
  *reinterpret_cast<bf16x8*>(Wf16 + gbase) = r;
  float s = v0.x * b0.x + v0.y * b0.y + v0.z * b0.z + v0.w * b0.w
          + v1.x * b1.x + v1.y * b1.y + v1.z * b1.z + v1.w * b1.w;
  s = wave_sum(s);
  __shared__ float red[4];
  if ((t & 63) == 0) red[t >> 6] = s;
  __syncthreads();
  if (t == 0) atomicAdd(beq + o, red[0] + red[1] + red[2] + red[3]);
}

// ---------------- W16 [c][i] f32 -> W16T [i][c] bf16 ------------------------------
__global__ void transpose_w16(const float* __restrict__ W, bf16_t* __restrict__ T)
{
  __shared__ bf16_t tile[64][65];
  const int cb = blockIdx.x * 64;
  const int ib = blockIdx.y * 64;
  const int tx = threadIdx.x & 63;
  const int ty = threadIdx.x >> 6;
#pragma unroll
  for (int r = ty; r < 64; r += 4)
    tile[r][tx] = (bf16_t)W[(size_t)(cb + r) * ID + ib + tx];
  __syncthreads();
#pragma unroll
  for (int r = ty; r < 64; r += 4)
    T[(size_t)(ib + r) * KC + cb + tx] = tile[tx][r];
}

// ---------------- x f32 -> bf16 ---------------------------------------------------
__global__ void conv_x(const float* __restrict__ X, bf16_t* __restrict__ X16)
{
  const size_t i = ((size_t)blockIdx.x * 256 + threadIdx.x) * 8;
  const float4 v0 = *(const float4*)(X + i);
  const float4 v1 = *(const float4*)(X + i + 4);
  bf16x8 r;
  r[0] = (bf16_t)v0.x; r[1] = (bf16_t)v0.y; r[2] = (bf16_t)v0.z; r[3] = (bf16_t)v0.w;
  r[4] = (bf16_t)v1.x; r[5] = (bf16_t)v1.y; r[6] = (bf16_t)v1.z; r[7] = (bf16_t)v1.w;
  *reinterpret_cast<bf16x8*>(X16 + i) = r;
}

// ---------------- reduce 4 K-split slabs -> Weq bf16 ------------------------------
__global__ void reduce_weq(const float* __restrict__ slabs, bf16_t* __restrict__ Weq)
{
  const size_t MN = (size_t)OD * ID;
  const size_t i = ((size_t)blockIdx.x * 256 + threadIdx.x) * 4;
  float4 a = *(const float4*)(slabs + i);
  float4 b = *(const float4*)(slabs + MN + i);
  float4 c = *(const float4*)(slabs + 2 * MN + i);
  float4 d = *(const float4*)(slabs + 3 * MN + i);
  bf16x4 r;
  r[0] = (bf16_t)(a.x + b.x + c.x + d.x);
  r[1] = (bf16_t)(a.y + b.y + c.y + d.y);
  r[2] = (bf16_t)(a.z + b.z + c.z + d.z);
  r[3] = (bf16_t)(a.w + b.w + c.w + d.w);
  *reinterpret_cast<bf16x4*>(Weq + i) = r;
}

// ---------------- bias + LayerNorm + exact GELU -----------------------------------
__global__ __launch_bounds__(256) void ln_gelu(
    const float* __restrict__ fused, const float* __restrict__ beq,
    const float* __restrict__ bfv, const float* __restrict__ gamma,
    const float* __restrict__ beta, float* __restrict__ out)
{
  const int row = blockIdx.x;
  const int t = threadIdx.x;
  const float* fr = fused + (size_t)row * OD;
  const int c0 = t * 8;
  float v[8];
  float s = 0.f, ss = 0.f;
#pragma unroll
  for (int j = 0; j < 2; ++j) {
    float4 x  = *(const float4*)(fr  + c0 + j * 4);
    float4 bq = *(const float4*)(beq + c0 + j * 4);
    float4 bb = *(const float4*)(bfv + c0 + j * 4);
    v[j * 4 + 0] = x.x + bq.x + bb.x;
    v[j * 4 + 1] = x.y + bq.y + bb.y;
    v[j * 4 + 2] = x.z + bq.z + bb.z;
    v[j * 4 + 3] = x.w + bq.w + bb.w;
#pragma unroll
    for (int e = 0; e < 4; ++e) { float w = v[j * 4 + e]; s += w; ss += w * w; }
  }
  s = wave_sum(s); ss = wave_sum(ss);
  __shared__ float rs[4], rss[4];
  if ((t & 63) == 0) { rs[t >> 6] = s; rss[t >> 6] = ss; }
  __syncthreads();
  const float S  = rs[0] + rs[1] + rs[2] + rs[3];
  const float SS = rss[0] + rss[1] + rss[2] + rss[3];
  const float mu   = S * (1.f / OD);
  const float var  = SS * (1.f / OD) - mu * mu;
  const float rstd = rsqrtf(var + 1e-5f);
#pragma unroll
  for (int j = 0; j < 2; ++j) {
    float4 g  = *(const float4*)(gamma + c0 + j * 4);
    float4 be = *(const float4*)(beta  + c0 + j * 4);
    float4 o;
    float xn;
    xn  = (v[j * 4 + 0] - mu) * rstd * g.x + be.x; o.x = 0.5f * xn * (1.f + erff(xn * 0.70710678118f));
    xn  = (v[j * 4 + 1] - mu) * rstd * g.y + be.y; o.y = 0.5f * xn * (1.f + erff(xn * 0.70710678118f));
    xn  = (v[j * 4 + 2] - mu) * rstd * g.z + be.z; o.z = 0.5f * xn * (1.f + erff(xn * 0.70710678118f));
    xn  = (v[j * 4 + 3] - mu) * rstd * g.w + be.w; o.w = 0.5f * xn * (1.f + erff(xn * 0.70710678118f));
    *(float4*)(out + (size_t)row * OD + c0 + j * 4) = o;
  }
}

extern "C" void kernel_launch(void* const* d_in, const int* in_sizes, int n_in,
                              void* d_out, int out_size, void* d_ws, size_t ws_size,
                              hipStream_t stream) {
  const float* x     = (const float*)d_in[0];
  const float* W16   = (const float*)d_in[1];
  const float* b16   = (const float*)d_in[2];
  const float* Wf    = (const float*)d_in[3];
  const float* bfv   = (const float*)d_in[4];
  const float* gamma = (const float*)d_in[5];
  const float* beta  = (const float*)d_in[6];
  float* out = (float*)d_out;

  char* ws = (char*)d_ws;
  bf16_t* W16T  = (bf16_t*)(ws);                 // [2048][32768] bf16, 128 MiB
  bf16_t* Wf16  = (bf16_t*)(ws + 134217728);     // [2048][32768] bf16, 128 MiB
  bf16_t* X16   = (bf16_t*)(ws + 268435456);     // [8192][2048] bf16, 32 MiB
  bf16_t* Weq   = (bf16_t*)(ws + 301989888);     // [2048][2048] bf16, 8 MiB
  float*  beq   = (float*)(ws + 310378496);      // [2048] f32
  float*  slabs = (float*)(ws + 310386688);      // 4 x 16 MiB f32; reused as fused
  float*  fused = slabs;

  hipMemsetAsync(beq, 0, OD * sizeof(float), stream);

  conv_wf_beq<<<dim3(16, 2048), 256, 0, stream>>>(Wf, b16, Wf16, beq);
  transpose_w16<<<dim3(KC / 64, ID / 64), 256, 0, stream>>>(W16, W16T);
  conv_x<<<(BSROWS * ID) / (256 * 8), 256, 0, stream>>>(x, X16);

  // GEMM1: Weq = Wf16 [2048][32768] * W16T^T, K-split 4 -> slabs (grid 256)
  gemm256<<<256, 512, 0, stream>>>(Wf16, W16T, slabs, OD, ID, KC, KC, KC / 4, 8, 64);
  reduce_weq<<<(OD * ID) / (256 * 4), 256, 0, stream>>>(slabs, Weq);

  // GEMM2: fused = X16 [8192][2048] * Weq^T [2048][2048] (grid 32x8 = 256)
  gemm256<<<256, 512, 0, stream>>>(X16, Weq, fused, BSROWS, OD, ID, ID, ID, 8, 256);

  ln_gelu<<<BSROWS, 256, 0, stream>>>(fused, beq, bfv, gamma, beta, out);
}

// Round 5
// 594.639 us; speedup vs baseline: 1.4806x; 1.0096x over previous
//
#include <hip/hip_runtime.h>
#include <hip/hip_bf16.h>
#include <math.h>

// QuantumNeuralLayer collapsed: fused = x @ Weq^T + beq, Weq = Wf @ W16r.
// R5: R4 pipeline + 2-bit LDS bank swizzle (slot ^= (row>>2)&3, both-sides:
// pre-swizzled global source for linear global_load_lds dest, XOR on ds_read).
// 16-lane fragment group now covers all 32 banks 2-deep (b128 floor).

typedef __bf16 bf16_t;
typedef __bf16 bf16x8 __attribute__((ext_vector_type(8)));
typedef __bf16 bf16x4 __attribute__((ext_vector_type(4)));
typedef float  f32x4  __attribute__((ext_vector_type(4)));

#define KC 32768
#define OD 2048
#define ID 2048
#define BSROWS 8192

#define GLL16(g, l) __builtin_amdgcn_global_load_lds( \
    (const __attribute__((address_space(1))) void*)(g), \
    (__attribute__((address_space(3))) void*)(l), 16, 0, 0)

__device__ __forceinline__ float wave_sum(float v) {
#pragma unroll
  for (int o = 32; o > 0; o >>= 1) v += __shfl_down(v, o, 64);
  return v;
}

__global__ __launch_bounds__(512, 1) void gemm256(
    const bf16_t* __restrict__ A, const bf16_t* __restrict__ B,
    float* __restrict__ C, int M, int N, int lda, int ldb,
    int Ks, int nbn, int mn)
{
  __shared__ char lds[131072];   // ring-4 slots: slot s at s*32768 (A 16K + B 16K)
  const int tid  = threadIdx.x;
  const int lane = tid & 63;
  const int wave = tid >> 6;

  // T1: bijective XCD swizzle (gridDim.x % 8 == 0)
  const int nwg = gridDim.x;
  const int per = nwg >> 3;
  const int swz = (blockIdx.x & 7) * per + (blockIdx.x >> 3);
  const int z   = swz / mn;
  const int rem = swz - z * mn;
  const int bm  = (rem / nbn) * 256;
  const int bn  = (rem % nbn) * 256;
  const int k0  = z * Ks;
  float* Cz = C + (size_t)z * ((size_t)M * (size_t)N);

  const int wr = wave >> 2, wc = wave & 3;
  const int wrbase = wr * 128, wcbase = wc * 64;
  const int frow   = lane & 15;
  const int slot16 = (lane >> 4) * 16;

  // staging: thread covers row tid>>2 (and +128); 16B slot pre-swizzled by
  // slot_src = (tid&3) ^ ((tid>>4)&3)  [row bits 2..3 = tid bits 4..5]
  const int srow = tid >> 2;
  const int scol = ((tid & 3) ^ ((tid >> 4) & 3)) * 8;
  const bf16_t* gA = A + (size_t)(bm + srow) * lda + k0 + scol;
  const bf16_t* gB = B + (size_t)(bn + srow) * ldb + k0 + scol;
  const int ldst = wave * 1024;  // + lane*16 implied by global_load_lds

  f32x4 acc[8][4] = {};
  bf16x8 afA[8], bgA[4], afB[8], bgB[4];
  const int NC = Ks >> 5;        // number of K=32 chunks (>= 8, even)

  // read side: same XOR on the 16B slot; row bits 2..3 == lane bits 2..3
  const int rdswz = slot16 ^ ((lane & 12) << 2);
  const int aoff = (wrbase + frow) * 64 + rdswz;
  const int boff = (wcbase + frow) * 64 + rdswz;

#define STAGE(c) do {                                             \
    char* Ab_ = lds + (((c) & 3) << 15);                          \
    char* Bb_ = Ab_ + 16384;                                      \
    const bf16_t* a_ = gA + (size_t)(c) * 32;                     \
    const bf16_t* b_ = gB + (size_t)(c) * 32;                     \
    GLL16(a_,                     Ab_ + ldst);                    \
    GLL16(a_ + (size_t)128 * lda, Ab_ + 8192 + ldst);             \
    GLL16(b_,                     Bb_ + ldst);                    \
    GLL16(b_ + (size_t)128 * ldb, Bb_ + 8192 + ldst);             \
  } while (0)

#define READ(c, af, bg) do {                                      \
    const char* ap_ = lds + (((c) & 3) << 15) + aoff;             \
    const char* bp_ = lds + (((c) & 3) << 15) + 16384 + boff;     \
    _Pragma("unroll")                                             \
    for (int n = 0; n < 4; ++n)                                   \
      bg[n] = *reinterpret_cast<const bf16x8*>(bp_ + n * 1024);   \
    _Pragma("unroll")                                             \
    for (int m = 0; m < 8; ++m)                                   \
      af[m] = *reinterpret_cast<const bf16x8*>(ap_ + m * 1024);   \
  } while (0)

#define MFMA32(af, bg) do {                                       \
    __builtin_amdgcn_s_setprio(1);                                \
    _Pragma("unroll")                                             \
    for (int m = 0; m < 8; ++m)                                   \
      _Pragma("unroll")                                           \
      for (int n = 0; n < 4; ++n)                                 \
        acc[m][n] = __builtin_amdgcn_mfma_f32_16x16x32_bf16(      \
            af[m], bg[n], acc[m][n], 0, 0, 0);                    \
    __builtin_amdgcn_s_setprio(0);                                \
  } while (0)

  // phase c body: MFMA chunk c on `cur` regs; read chunk c+1 into `nxt` regs.
#define PHASE(c, afC, bgC, afN, bgN) do {                         \
    if ((c) < NC - 3)       asm volatile("s_waitcnt vmcnt(8)" ::: "memory"); \
    else if ((c) == NC - 3) asm volatile("s_waitcnt vmcnt(4)" ::: "memory"); \
    else if ((c) == NC - 2) asm volatile("s_waitcnt vmcnt(0)" ::: "memory"); \
    __builtin_amdgcn_s_barrier();                                 \
    if ((c) + 4 < NC) STAGE((c) + 4);                             \
    if ((c) + 1 < NC) READ((c) + 1, afN, bgN);                    \
    MFMA32(afC, bgC);                                             \
  } while (0)

  // prologue: stage chunks 0-3, wait chunk 0 landed, read it
  STAGE(0); STAGE(1); STAGE(2); STAGE(3);
  asm volatile("s_waitcnt vmcnt(12)" ::: "memory");
  __builtin_amdgcn_s_barrier();
  READ(0, afA, bgA);

#pragma unroll 1
  for (int c = 0; c < NC; c += 2) {
    PHASE(c,     afA, bgA, afB, bgB);
    PHASE(c + 1, afB, bgB, afA, bgA);
  }
#undef PHASE
#undef MFMA32
#undef READ
#undef STAGE

  // C/D layout (m89-verified): col = lane&15, row = (lane>>4)*4 + j
  const int cr = (lane >> 4) * 4, cc = lane & 15;
#pragma unroll
  for (int m = 0; m < 8; ++m)
#pragma unroll
    for (int n = 0; n < 4; ++n) {
      size_t base = (size_t)(bm + wrbase + m * 16 + cr) * N + (bn + wcbase + n * 16 + cc);
#pragma unroll
      for (int j = 0; j < 4; ++j)
        Cz[base + (size_t)j * N] = acc[m][n][j];
    }
}

// ---------------- Wf f32 -> bf16, and beq partial = sum_c b16[c]*Wf[o,c] ----------
__global__ void conv_wf_beq(const float* __restrict__ Wf, const float* __restrict__ b16,
                            bf16_t* __restrict__ Wf16, float* __restrict__ beq)
{
  const int o  = blockIdx.y;
  const int cb = blockIdx.x * 2048;
  const int t  = threadIdx.x;
  const size_t gbase = (size_t)o * KC + cb + t * 8;
  const float4 v0 = *(const float4*)(Wf + gbase);
  const float4 v1 = *(const float4*)(Wf + gbase + 4);
  const float4 b0 = *(const float4*)(b16 + cb + t * 8);
  const float4 b1 = *(const float4*)(b16 + cb + t * 8 + 4);
  bf16x8 r;
  r[0] = (bf16_t)v0.x; r[1] = (bf16_t)v0.y; r[2] = (bf16_t)v0.z; r[3] = (bf16_t)v0.w;
  r[4] = (bf16_t)v1.x; r[5] = (bf16_t)v1.y; r[6] = (bf16_t)v1.z; r[7] = (bf16_t)v1.w;
  *reinterpret_cast<bf16x8*>(Wf16 + gbase) = r;
  float s = v0.x * b0.x + v0.y * b0.y + v0.z * b0.z + v0.w * b0.w
          + v1.x * b1.x + v1.y * b1.y + v1.z * b1.z + v1.w * b1.w;
  s = wave_sum(s);
  __shared__ float red[4];
  if ((t & 63) == 0) red[t >> 6] = s;
  __syncthreads();
  if (t == 0) atomicAdd(beq + o, red[0] + red[1] + red[2] + red[3]);
}

// ---------------- W16 [c][i] f32 -> W16T [i][c] bf16 (vectorized writes) ----------
__global__ void transpose_w16(const float* __restrict__ W, bf16_t* __restrict__ T)
{
  __shared__ bf16_t tile[64][65];
  const int cb = blockIdx.x * 64;
  const int ib = blockIdx.y * 64;
  const int tx = threadIdx.x & 63;
  const int ty = threadIdx.x >> 6;
#pragma unroll
  for (int r = ty; r < 64; r += 4)
    tile[r][tx] = (bf16_t)W[(size_t)(cb + r) * ID + ib + tx];
  __syncthreads();
  // write: thread -> output row ib + (t>>3) (+32), 8 contiguous cols, 16B store
  const int orow = threadIdx.x >> 3;
  const int oc8  = (threadIdx.x & 7) * 8;
#pragma unroll
  for (int rr = 0; rr < 2; ++rr) {
    const int r = orow + rr * 32;
    bf16x8 v;
#pragma unroll
    for (int j = 0; j < 8; ++j) v[j] = tile[oc8 + j][r];
    *reinterpret_cast<bf16x8*>(T + (size_t)(ib + r) * KC + cb + oc8) = v;
  }
}

// ---------------- x f32 -> bf16 ---------------------------------------------------
__global__ void conv_x(const float* __restrict__ X, bf16_t* __restrict__ X16)
{
  const size_t i = ((size_t)blockIdx.x * 256 + threadIdx.x) * 8;
  const float4 v0 = *(const float4*)(X + i);
  const float4 v1 = *(const float4*)(X + i + 4);
  bf16x8 r;
  r[0] = (bf16_t)v0.x; r[1] = (bf16_t)v0.y; r[2] = (bf16_t)v0.z; r[3] = (bf16_t)v0.w;
  r[4] = (bf16_t)v1.x; r[5] = (bf16_t)v1.y; r[6] = (bf16_t)v1.z; r[7] = (bf16_t)v1.w;
  *reinterpret_cast<bf16x8*>(X16 + i) = r;
}

// ---------------- reduce 4 K-split slabs -> Weq bf16 ------------------------------
__global__ void reduce_weq(const float* __restrict__ slabs, bf16_t* __restrict__ Weq)
{
  const size_t MN = (size_t)OD * ID;
  const size_t i = ((size_t)blockIdx.x * 256 + threadIdx.x) * 4;
  float4 a = *(const float4*)(slabs + i);
  float4 b = *(const float4*)(slabs + MN + i);
  float4 c = *(const float4*)(slabs + 2 * MN + i);
  float4 d = *(const float4*)(slabs + 3 * MN + i);
  bf16x4 r;
  r[0] = (bf16_t)(a.x + b.x + c.x + d.x);
  r[1] = (bf16_t)(a.y + b.y + c.y + d.y);
  r[2] = (bf16_t)(a.z + b.z + c.z + d.z);
  r[3] = (bf16_t)(a.w + b.w + c.w + d.w);
  *reinterpret_cast<bf16x4*>(Weq + i) = r;
}

// ---------------- bias + LayerNorm + exact GELU -----------------------------------
__global__ __launch_bounds__(256) void ln_gelu(
    const float* __restrict__ fused, const float* __restrict__ beq,
    const float* __restrict__ bfv, const float* __restrict__ gamma,
    const float* __restrict__ beta, float* __restrict__ out)
{
  const int row = blockIdx.x;
  const int t = threadIdx.x;
  const float* fr = fused + (size_t)row * OD;
  const int c0 = t * 8;
  float v[8];
  float s = 0.f, ss = 0.f;
#pragma unroll
  for (int j = 0; j < 2; ++j) {
    float4 x  = *(const float4*)(fr  + c0 + j * 4);
    float4 bq = *(const float4*)(beq + c0 + j * 4);
    float4 bb = *(const float4*)(bfv + c0 + j * 4);
    v[j * 4 + 0] = x.x + bq.x + bb.x;
    v[j * 4 + 1] = x.y + bq.y + bb.y;
    v[j * 4 + 2] = x.z + bq.z + bb.z;
    v[j * 4 + 3] = x.w + bq.w + bb.w;
#pragma unroll
    for (int e = 0; e < 4; ++e) { float w = v[j * 4 + e]; s += w; ss += w * w; }
  }
  s = wave_sum(s); ss = wave_sum(ss);
  __shared__ float rs[4], rss[4];
  if ((t & 63) == 0) { rs[t >> 6] = s; rss[t >> 6] = ss; }
  __syncthreads();
  const float S  = rs[0] + rs[1] + rs[2] + rs[3];
  const float SS = rss[0] + rss[1] + rss[2] + rss[3];
  const float mu   = S * (1.f / OD);
  const float var  = SS * (1.f / OD) - mu * mu;
  const float rstd = rsqrtf(var + 1e-5f);
#pragma unroll
  for (int j = 0; j < 2; ++j) {
    float4 g  = *(const float4*)(gamma + c0 + j * 4);
    float4 be = *(const float4*)(beta  + c0 + j * 4);
    float4 o;
    float xn;
    xn  = (v[j * 4 + 0] - mu) * rstd * g.x + be.x; o.x = 0.5f * xn * (1.f + erff(xn * 0.70710678118f));
    xn  = (v[j * 4 + 1] - mu) * rstd * g.y + be.y; o.y = 0.5f * xn * (1.f + erff(xn * 0.70710678118f));
    xn  = (v[j * 4 + 2] - mu) * rstd * g.z + be.z; o.z = 0.5f * xn * (1.f + erff(xn * 0.70710678118f));
    xn  = (v[j * 4 + 3] - mu) * rstd * g.w + be.w; o.w = 0.5f * xn * (1.f + erff(xn * 0.70710678118f));
    *(float4*)(out + (size_t)row * OD + c0 + j * 4) = o;
  }
}

extern "C" void kernel_launch(void* const* d_in, const int* in_sizes, int n_in,
                              void* d_out, int out_size, void* d_ws, size_t ws_size,
                              hipStream_t stream) {
  const float* x     = (const float*)d_in[0];
  const float* W16   = (const float*)d_in[1];
  const float* b16   = (const float*)d_in[2];
  const float* Wf    = (const float*)d_in[3];
  const float* bfv   = (const float*)d_in[4];
  const float* gamma = (const float*)d_in[5];
  const float* beta  = (const float*)d_in[6];
  float* out = (float*)d_out;

  char* ws = (char*)d_ws;
  bf16_t* W16T  = (bf16_t*)(ws);                 // [2048][32768] bf16, 128 MiB
  bf16_t* Wf16  = (bf16_t*)(ws + 134217728);     // [2048][32768] bf16, 128 MiB
  bf16_t* X16   = (bf16_t*)(ws + 268435456);     // [8192][2048] bf16, 32 MiB
  bf16_t* Weq   = (bf16_t*)(ws + 301989888);     // [2048][2048] bf16, 8 MiB
  float*  beq   = (float*)(ws + 310378496);      // [2048] f32
  float*  slabs = (float*)(ws + 310386688);      // 4 x 16 MiB f32; reused as fused
  float*  fused = slabs;

  hipMemsetAsync(beq, 0, OD * sizeof(float), stream);

  conv_wf_beq<<<dim3(16, 2048), 256, 0, stream>>>(Wf, b16, Wf16, beq);
  transpose_w16<<<dim3(KC / 64, ID / 64), 256, 0, stream>>>(W16, W16T);
  conv_x<<<(BSROWS * ID) / (256 * 8), 256, 0, stream>>>(x, X16);

  // GEMM1: Weq = Wf16 [2048][32768] * W16T^T, K-split 4 -> slabs (grid 256)
  gemm256<<<256, 512, 0, stream>>>(Wf16, W16T, slabs, OD, ID, KC, KC, KC / 4, 8, 64);
  reduce_weq<<<(OD * ID) / (256 * 4), 256, 0, stream>>>(slabs, Weq);

  // GEMM2: fused = X16 [8192][2048] * Weq^T [2048][2048] (grid 32x8 = 256)
  gemm256<<<256, 512, 0, stream>>>(X16, Weq, fused, BSROWS, OD, ID, ID, ID, 8, 256);

  ln_gelu<<<BSROWS, 256, 0, stream>>>(fused, beq, bfv, gamma, beta, out);
}